// Round 6
// baseline (43036.841 us; speedup 1.0000x reference)
//
#include <hip/hip_runtime.h>

constexpr int kH = 1024;   // hidden
constexpr int kT = 512;    // encoder steps
constexpr int kP = 96;     // decoder steps
constexpr int kB = 256;    // batch
constexpr int kSteps = kT + kP;
constexpr int UN = 16;     // hidden units per block
constexpr int BT = 64;     // batch tile per block
constexpr unsigned NB = 256;  // grid size

__device__ __forceinline__ float sig_(float x) { return 1.0f / (1.0f + __expf(-x)); }
__device__ __forceinline__ float tanh_(float x) {
  float e = __expf(-2.0f * fabsf(x));
  float t = (1.0f - e) / (1.0f + e);
  return copysignf(t, x);
}

// Agent-scope relaxed ops: sc-flagged, bypass non-coherent per-XCD L2,
// served by L3. Data path for all cross-block state (h, xT, gpart).
__device__ __forceinline__ float gload(const float* p) {
  return __hip_atomic_load(const_cast<float*>(p), __ATOMIC_RELAXED,
                           __HIP_MEMORY_SCOPE_AGENT);
}
__device__ __forceinline__ void gstore(float* p, float v) {
  __hip_atomic_store(p, v, __ATOMIC_RELAXED, __HIP_MEMORY_SCOPE_AGENT);
}

// Lightweight grid barrier (no L2 maintenance). __syncthreads drains vmcnt
// so arrival implies this block's sc-stores reached the coherence point.
__device__ __forceinline__ void gbar(unsigned* cnt, unsigned target) {
  __syncthreads();
  if (threadIdx.x == 0) {
    __hip_atomic_fetch_add(cnt, 1u, __ATOMIC_RELAXED, __HIP_MEMORY_SCOPE_AGENT);
    while (__hip_atomic_load(cnt, __ATOMIC_RELAXED, __HIP_MEMORY_SCOPE_AGENT) < target)
      __builtin_amdgcn_s_sleep(2);
  }
  __syncthreads();
}

__global__ void zero_cnt(unsigned* cnt) { if (threadIdx.x == 0) *cnt = 0u; }

// grid = 256 blocks x 1024 threads = 64 rowgroups x 4 batch-tiles.
// XCD swizzle: rg = (bid&7)*8 + (bid>>5) keeps the 4 tiles of a rowgroup on
// one XCD (shared 256KB weight slice stays L2-resident; 2MB/XCD total).
// Block (rg,tile): units j0..j0+15, batches b0..b0+63.
// GEMM: wave wv (0..15) covers ALL 64 gate rows for DISJOINT k-slice
// [64wv,64wv+64), lane = batch. acc[64] in regs; 16 wave-partials combined
// into part[4][64][64] via 4 serialized phases (deterministic, no atomics).
// Update: thread (unit=wv, batch=lane).
__global__ void __launch_bounds__(1024, 4)
lstm5(const float* __restrict__ xin,   // [B][T]
      const float* __restrict__ eWih,  // [4H]
      const float* __restrict__ eWhh,  // [4H][H]
      const float* __restrict__ eb,    // [4H]
      const float* __restrict__ h0,    // [H]
      const float* __restrict__ c0,    // [H]
      const float* __restrict__ dWih,
      const float* __restrict__ dWhh,
      const float* __restrict__ db,
      const float* __restrict__ outW,  // [H]
      const float* __restrict__ outb,  // [1]
      float* __restrict__ out,         // [B][P]
      float* __restrict__ hA,          // ws: hT ping [H][B]
      float* __restrict__ hB,          // ws: hT pong [H][B]
      float* __restrict__ xT,          // ws: [T][B]
      float* __restrict__ gpart,       // ws: [2][4][64][64] dec partials
      unsigned* __restrict__ cnt)      // ws: barrier counter (pre-zeroed)
{
  const int tid  = threadIdx.x;
  const int bid  = blockIdx.x;
  const int rg   = (bid & 7) * 8 + (bid >> 5);     // rowgroup 0..63
  const int tile = (bid >> 3) & 3;                 // batch tile 0..3
  const int j0   = rg * UN;
  const int b0   = tile * BT;
  const int lane = tid & 63;
  const int wv   = __builtin_amdgcn_readfirstlane(tid >> 6);  // 0..15

  __shared__ float part[4][64][64];   // 64 KB  combined gate partials
  __shared__ float decl[16][64];      // 4 KB   reduce scratch
  __shared__ float ybuf[64];          // decoder feedback for this tile

  // ---- one-time init ------------------------------------------------------
  gstore(&hA[(j0 + wv) * kB + b0 + lane], h0[j0 + wv]);
  float cReg    = c0[j0 + wv];
  float outWreg = outW[j0 + wv];
  const float outb0 = outb[0];
  {  // transpose x: xT[t*256+b] = xin[b*512+t]
    int g = bid * 1024 + tid;
    if (g < kT * kB) gstore(&xT[g], xin[(g & 255) * kT + (g >> 8)]);
  }

  const float* __restrict__ Whh  = eWhh;
  const float* __restrict__ Wih  = eWih;
  const float* __restrict__ bias = eb;
  float* hc = hA;
  float* hn = hB;

  unsigned bt = NB;
  gbar(cnt, bt); bt += NB;

  // ---- time loop ----------------------------------------------------------
  for (int step = 0; step < kSteps; ++step) {
    const bool dec = (step >= kT);
    if (step == kT) { Whh = dWhh; Wih = dWih; bias = db; }

    // phase A: reduce previous decoder step's projection partials -> y
    if (dec && step > kT) {
      const int rp = (step - 1 - kT) & 1;
      const float* gp = gpart + (rp * 4 + tile) * 64 * 64;   // [rg][b]
      float p4 = 0.f;
#pragma unroll
      for (int i = 0; i < 4; ++i)
        p4 += gload(&gp[(wv * 4 + i) * 64 + lane]);          // fixed order
      decl[wv][lane] = p4;
      __syncthreads();
      if (tid < 64) {
        float y = outb0;
#pragma unroll
        for (int c2 = 0; c2 < 16; ++c2) y += decl[c2][tid];  // fixed order
        ybuf[tid] = y;
        if (rg == 0) out[(b0 + tid) * kP + (step - 1 - kT)] = y;
      }
    }

    // -- GEMM: wave wv, k in [64wv, 64wv+64), all 64 rows, batch b0+lane
    float acc[64];
#pragma unroll
    for (int r = 0; r < 64; ++r) acc[r] = 0.f;

    const int k0 = wv * 64;
    for (int kk = 0; kk < 64; kk += 8) {
      const int k = k0 + kk;
      float h8[8];
#pragma unroll
      for (int d = 0; d < 8; ++d)
        h8[d] = gload(&hc[(k + d) * kB + b0 + lane]);        // coalesced 256B
#pragma unroll
      for (int r = 0; r < 64; ++r) {
        const float* wp = &Whh[((r >> 4) * kH + j0 + (r & 15)) * kH + k];
        float4 wa = *(const float4*)wp;                      // uniform->s_load
        float4 wb = *(const float4*)(wp + 4);
        acc[r] = fmaf(wa.x, h8[0], acc[r]);
        acc[r] = fmaf(wa.y, h8[1], acc[r]);
        acc[r] = fmaf(wa.z, h8[2], acc[r]);
        acc[r] = fmaf(wa.w, h8[3], acc[r]);
        acc[r] = fmaf(wb.x, h8[4], acc[r]);
        acc[r] = fmaf(wb.y, h8[5], acc[r]);
        acc[r] = fmaf(wb.z, h8[6], acc[r]);
        acc[r] = fmaf(wb.w, h8[7], acc[r]);
      }
    }

    // -- combine 16 wave-partials into part[4] (4 phases, deterministic)
    const int slot = wv & 3, ph = wv >> 2;
    if (ph == 0) {
#pragma unroll
      for (int r = 0; r < 64; ++r) part[slot][r][lane] = acc[r];
    }
    __syncthreads();
    if (ph == 1) {
#pragma unroll
      for (int r = 0; r < 64; ++r) part[slot][r][lane] += acc[r];
    }
    __syncthreads();
    if (ph == 2) {
#pragma unroll
      for (int r = 0; r < 64; ++r) part[slot][r][lane] += acc[r];
    }
    __syncthreads();
    if (ph == 3) {
#pragma unroll
      for (int r = 0; r < 64; ++r) part[slot][r][lane] += acc[r];
    }
    __syncthreads();

    // -- cell update: thread (unit = wv, batch = b0 + lane)
    float xv;
    if (!dec)            xv = gload(&xT[step * kB + b0 + lane]);
    else if (step == kT) xv = gload(&xT[(kT - 1) * kB + b0 + lane]);
    else                 xv = ybuf[lane];

    float g4[4];
#pragma unroll
    for (int g = 0; g < 4; ++g) {
      const int r = g * UN + wv;
      float s = ((part[0][r][lane] + part[1][r][lane]) +
                 part[2][r][lane]) + part[3][r][lane];       // fixed order
      const int grow = g * kH + j0 + wv;                     // wave-uniform
      g4[g] = s + bias[grow] + xv * Wih[grow];
    }
    float ig = sig_(g4[0]), fg = sig_(g4[1]);
    float gg = tanh_(g4[2]), og = sig_(g4[3]);
    cReg = fg * cReg + ig * gg;
    float hv = og * tanh_(cReg);
    gstore(&hn[(j0 + wv) * kB + b0 + lane], hv);             // coalesced

    if (dec) {  // projection partial for this (rg, tile)
      decl[wv][lane] = hv * outWreg;
      __syncthreads();
      if (tid < 64) {
        float p = 0.f;
#pragma unroll
        for (int u = 0; u < 16; ++u) p += decl[u][tid];      // fixed order
        const int wp2 = (step - kT) & 1;
        gstore(&gpart[((wp2 * 4 + tile) * 64 + rg) * 64 + tid], p);
      }
    }

    gbar(cnt, bt); bt += NB;           // h (+gpart) visible grid-wide
    float* t2 = hc; hc = hn; hn = t2;
  }

  // ---- epilogue: final decoder output p = kP-1 (gpart visible post-barrier)
  if (rg == 0) {
    const int rp = (kP - 1) & 1;
    const float* gp = gpart + (rp * 4 + tile) * 64 * 64;
    float p4 = 0.f;
#pragma unroll
    for (int i = 0; i < 4; ++i)
      p4 += gload(&gp[(wv * 4 + i) * 64 + lane]);
    decl[wv][lane] = p4;
    __syncthreads();
    if (tid < 64) {
      float y = outb0;
#pragma unroll
      for (int c2 = 0; c2 < 16; ++c2) y += decl[c2][tid];
      out[(b0 + tid) * kP + (kP - 1)] = y;
    }
  }
}

extern "C" void kernel_launch(void* const* d_in, const int* in_sizes, int n_in,
                              void* d_out, int out_size, void* d_ws, size_t ws_size,
                              hipStream_t stream) {
  const float* xin  = (const float*)d_in[0];
  const float* eWih = (const float*)d_in[1];
  const float* eWhh = (const float*)d_in[2];
  const float* eb   = (const float*)d_in[3];
  const float* h0   = (const float*)d_in[4];
  const float* c0   = (const float*)d_in[5];
  const float* dWih = (const float*)d_in[6];
  const float* dWhh = (const float*)d_in[7];
  const float* db   = (const float*)d_in[8];
  const float* outW = (const float*)d_in[9];
  const float* outb = (const float*)d_in[10];
  float* out = (float*)d_out;

  float* wsf    = (float*)d_ws;
  float* hA     = wsf;                          // 1024*256
  float* hB     = hA + kH * kB;                 // 1024*256
  float* xT     = hB + kH * kB;                 // 512*256
  float* gpart  = xT + kT * kB;                 // 2*4*64*64
  unsigned* cnt = (unsigned*)(gpart + 2 * 4 * 64 * 64);

  zero_cnt<<<1, 64, 0, stream>>>(cnt);

  void* args[] = {(void*)&xin, (void*)&eWih, (void*)&eWhh, (void*)&eb,
                  (void*)&h0, (void*)&c0, (void*)&dWih, (void*)&dWhh,
                  (void*)&db, (void*)&outW, (void*)&outb, (void*)&out,
                  (void*)&hA, (void*)&hB, (void*)&xT, (void*)&gpart,
                  (void*)&cnt};
  hipLaunchCooperativeKernel((const void*)lstm5, dim3(256), dim3(1024),
                             args, 0, stream);
}

// Round 7
// 29507.260 us; speedup vs baseline: 1.4585x; 1.4585x over previous
//
#include <hip/hip_runtime.h>

constexpr int kH = 1024;   // hidden
constexpr int kT = 512;    // encoder steps
constexpr int kP = 96;     // decoder steps
constexpr int kB = 256;    // batch
constexpr int kSteps = kT + kP;
constexpr unsigned NB = 256;  // grid size

__device__ __forceinline__ float sig_(float x) { return 1.0f / (1.0f + __expf(-x)); }
__device__ __forceinline__ float tanh_(float x) {
  float e = __expf(-2.0f * fabsf(x));
  float t = (1.0f - e) / (1.0f + e);
  return copysignf(t, x);
}

// Agent-scope relaxed ops: bypass non-coherent per-XCD L2, served by the
// memory-side L3 (always coherent). Path for all cross-block state.
__device__ __forceinline__ float gload(const float* p) {
  return __hip_atomic_load(const_cast<float*>(p), __ATOMIC_RELAXED,
                           __HIP_MEMORY_SCOPE_AGENT);
}
__device__ __forceinline__ void gstore(float* p, float v) {
  __hip_atomic_store(p, v, __ATOMIC_RELAXED, __HIP_MEMORY_SCOPE_AGENT);
}

// Lightweight grid barrier (no L2 maintenance). __syncthreads drains vmcnt so
// arrival implies this block's sc-stores reached the coherence point.
__device__ __forceinline__ void gbar(unsigned* cnt, unsigned target) {
  __syncthreads();
  if (threadIdx.x == 0) {
    __hip_atomic_fetch_add(cnt, 1u, __ATOMIC_RELAXED, __HIP_MEMORY_SCOPE_AGENT);
    while (__hip_atomic_load(cnt, __ATOMIC_RELAXED, __HIP_MEMORY_SCOPE_AGENT) < target)
      __builtin_amdgcn_s_sleep(2);
  }
  __syncthreads();
}

__global__ void zero_cnt(unsigned* cnt) { if (threadIdx.x == 0) *cnt = 0u; }

// grid = 256 blocks x 1024 threads = 64 rowgroups x 4 batch-tiles.
// bid -> XCD = bid&7; rg = (bid&7)*8 + ((bid>>3)&7) so the 4 tiles of a
// rowgroup share an XCD (weight slice 2MB/XCD, L2-resident).
// Block (rg,tile): units rg*16..+16 (64 gate rows), batches b0..b0+63.
// Per step: 8 chunks of 128 k staged hc->LDS (each h read ONCE per block,
// coalesced; double-buffered; loads issued before compute to hide L3 latency).
// Waves: 8 row-octets x 2 k-halves; thread acc[8]; unique-slot partials
// part[kh][row][b] summed in fixed order -> deterministic, no atomics.
__global__ void __launch_bounds__(1024, 4)
lstm6(const float* __restrict__ xin,   // [B][T]
      const float* __restrict__ eWih,  // [4H]
      const float* __restrict__ eWhh,  // [4H][H]
      const float* __restrict__ eb,    // [4H]
      const float* __restrict__ h0,    // [H]
      const float* __restrict__ c0,    // [H]
      const float* __restrict__ dWih,
      const float* __restrict__ dWhh,
      const float* __restrict__ db,
      const float* __restrict__ outW,  // [H]
      const float* __restrict__ outb,  // [1]
      float* __restrict__ out,         // [B][P]
      float* __restrict__ hA,          // ws: hT ping [H][B]
      float* __restrict__ hB,          // ws: hT pong [H][B]
      float* __restrict__ xT,          // ws: [T][B]
      float* __restrict__ gpart,       // ws: [2][4][64][64] dec partials
      unsigned* __restrict__ cnt)      // ws: barrier counter (pre-zeroed)
{
  const int tid  = threadIdx.x;
  const int bid  = blockIdx.x;
  const int rg   = (bid & 7) * 8 + ((bid >> 3) & 7);   // rowgroup 0..63
  const int tile = bid >> 6;                           // batch tile 0..3
  const int b0   = tile * 64;
  const int lane = tid & 63;
  const int wv   = __builtin_amdgcn_readfirstlane(tid >> 6);  // 0..15
  const int kh   = wv & 1;          // k-half of chunk (64 k)
  const int ro   = wv >> 1;         // row-octet 0..7
  const int u    = wv;              // update phase: unit 0..15

  __shared__ float hbuf[2][128][65];   // 66.6KB staged h chunks (padded rows)
  __shared__ float part[2][64][64];    // 32KB  k-half partials
  __shared__ float decl[16][64];       // 4KB   reduce scratch
  __shared__ float ybuf[64];           // decoder feedback

  // ---- one-time init ------------------------------------------------------
  gstore(&hA[(rg * 16 + u) * kB + b0 + lane], h0[rg * 16 + u]);
  float cReg = c0[rg * 16 + u];
  const float outWreg = outW[rg * 16 + u];
  const float outb0   = outb[0];
  {  // transpose x: xT[t*256+b] = xin[b*512+t]
    int g = bid * 1024 + tid;
    if (g < kT * kB) gstore(&xT[g], xin[(g & 255) * kT + (g >> 8)]);
  }

  const float* Whh  = eWhh;
  const float* Wih  = eWih;
  const float* bias = eb;
  float* hc = hA;
  float* hn = hB;

  unsigned bt = NB;
  gbar(cnt, bt); bt += NB;

  // ---- time loop ----------------------------------------------------------
  for (int step = 0; step < kSteps; ++step) {
    const bool dec = (step >= kT);
    if (step == kT) { Whh = dWhh; Wih = dWih; bias = db; }

    // this wave's 8 weight-row pointers (uniform -> SGPR)
    const float* rowp[8];
#pragma unroll
    for (int rr = 0; rr < 8; ++rr) {
      const int lr = ro * 8 + rr;                        // local row 0..63
      rowp[rr] = Whh + (size_t)(((lr >> 4) << 10) + rg * 16 + (lr & 15)) * kH;
    }

    float acc[8];
#pragma unroll
    for (int rr = 0; rr < 8; ++rr) acc[rr] = 0.f;

    // stage chunk 0: wave wv loads k-rows wv*8..+8, col=lane (256B coalesced)
    float st[8];
    {
      const float* sp = hc + (0 * 128 + wv * 8) * kB + b0 + lane;
#pragma unroll
      for (int j = 0; j < 8; ++j) st[j] = gload(&sp[j * kB]);
    }

    // decoder phase A: reduce previous step's projection partials -> y
    if (dec && step > kT) {
      const int rp = (step - 1 - kT) & 1;
      const float* gp = gpart + (rp * 4 + tile) * 64 * 64;
      float p4 = 0.f;
#pragma unroll
      for (int i = 0; i < 4; ++i)
        p4 += gload(&gp[(wv * 4 + i) * 64 + lane]);      // fixed order
      decl[wv][lane] = p4;
      __syncthreads();
      if (tid < 64) {
        float y = outb0;
#pragma unroll
        for (int c2 = 0; c2 < 16; ++c2) y += decl[c2][tid];
        ybuf[tid] = y;
        if (rg == 0) out[(b0 + tid) * kP + (step - 1 - kT)] = y;
      }
    }

#pragma unroll
    for (int j = 0; j < 8; ++j) hbuf[0][wv * 8 + j][lane] = st[j];
    __syncthreads();

    // -- chunk loop: compute buf[c&1], prefetch chunk c+1
    for (int c = 0; c < 8; ++c) {
      const int bsel = c & 1;
      if (c < 7) {
        const float* sp = hc + ((c + 1) * 128 + wv * 8) * kB + b0 + lane;
#pragma unroll
        for (int j = 0; j < 8; ++j) st[j] = gload(&sp[j * kB]);
      }
      const int gk0 = c * 128 + kh * 64;
      for (int kk = 0; kk < 64; kk += 4) {
        const int kl = kh * 64 + kk;
        float h0v = hbuf[bsel][kl + 0][lane];
        float h1v = hbuf[bsel][kl + 1][lane];
        float h2v = hbuf[bsel][kl + 2][lane];
        float h3v = hbuf[bsel][kl + 3][lane];
#pragma unroll
        for (int rr = 0; rr < 8; ++rr) {
          const float4 w4 = *(const float4*)(rowp[rr] + gk0 + kk);  // s_load
          acc[rr] = fmaf(w4.x, h0v, acc[rr]);
          acc[rr] = fmaf(w4.y, h1v, acc[rr]);
          acc[rr] = fmaf(w4.z, h2v, acc[rr]);
          acc[rr] = fmaf(w4.w, h3v, acc[rr]);
        }
      }
      if (c < 7) {
#pragma unroll
        for (int j = 0; j < 8; ++j) hbuf[bsel ^ 1][wv * 8 + j][lane] = st[j];
      }
      __syncthreads();
    }

    // -- k-half partials to unique slots
#pragma unroll
    for (int rr = 0; rr < 8; ++rr) part[kh][ro * 8 + rr][lane] = acc[rr];
    __syncthreads();

    // -- cell update: thread (unit u, batch b0+lane)
    float xv;
    if (!dec)            xv = gload(&xT[step * kB + b0 + lane]);
    else if (step == kT) xv = gload(&xT[(kT - 1) * kB + b0 + lane]);
    else                 xv = ybuf[lane];

    float g4[4];
#pragma unroll
    for (int g = 0; g < 4; ++g) {
      const int lr = g * 16 + u;
      const float s = part[0][lr][lane] + part[1][lr][lane];  // fixed order
      const int grow = (g << 10) + rg * 16 + u;               // wave-uniform
      g4[g] = s + bias[grow] + xv * Wih[grow];
    }
    float ig = sig_(g4[0]), fg = sig_(g4[1]);
    float gg = tanh_(g4[2]), og = sig_(g4[3]);
    cReg = fg * cReg + ig * gg;
    float hv = og * tanh_(cReg);
    gstore(&hn[(rg * 16 + u) * kB + b0 + lane], hv);          // coalesced

    if (dec) {  // projection partial for this (rg, tile)
      decl[u][lane] = hv * outWreg;
      __syncthreads();
      if (tid < 64) {
        float p = 0.f;
#pragma unroll
        for (int u2 = 0; u2 < 16; ++u2) p += decl[u2][tid];   // fixed order
        gstore(&gpart[(((step - kT) & 1) * 4 + tile) * 64 * 64 + rg * 64 + tid], p);
      }
    }

    gbar(cnt, bt); bt += NB;          // h (+gpart) visible grid-wide
    float* t2 = hc; hc = hn; hn = t2;
  }

  // ---- epilogue: final decoder output p = kP-1
  {
    const int rp = (kP - 1) & 1;
    const float* gp = gpart + (rp * 4 + tile) * 64 * 64;
    float p4 = 0.f;
#pragma unroll
    for (int i = 0; i < 4; ++i)
      p4 += gload(&gp[(wv * 4 + i) * 64 + lane]);
    decl[wv][lane] = p4;
    __syncthreads();
    if (tid < 64 && rg == 0) {
      float y = outb0;
#pragma unroll
      for (int c2 = 0; c2 < 16; ++c2) y += decl[c2][tid];
      out[(b0 + tid) * kP + (kP - 1)] = y;
    }
  }
}

extern "C" void kernel_launch(void* const* d_in, const int* in_sizes, int n_in,
                              void* d_out, int out_size, void* d_ws, size_t ws_size,
                              hipStream_t stream) {
  const float* xin  = (const float*)d_in[0];
  const float* eWih = (const float*)d_in[1];
  const float* eWhh = (const float*)d_in[2];
  const float* eb   = (const float*)d_in[3];
  const float* h0   = (const float*)d_in[4];
  const float* c0   = (const float*)d_in[5];
  const float* dWih = (const float*)d_in[6];
  const float* dWhh = (const float*)d_in[7];
  const float* db   = (const float*)d_in[8];
  const float* outW = (const float*)d_in[9];
  const float* outb = (const float*)d_in[10];
  float* out = (float*)d_out;

  float* wsf    = (float*)d_ws;
  float* hA     = wsf;                          // 1024*256
  float* hB     = hA + kH * kB;                 // 1024*256
  float* xT     = hB + kH * kB;                 // 512*256
  float* gpart  = xT + kT * kB;                 // 2*4*64*64
  unsigned* cnt = (unsigned*)(gpart + 2 * 4 * 64 * 64);

  zero_cnt<<<1, 64, 0, stream>>>(cnt);

  void* args[] = {(void*)&xin, (void*)&eWih, (void*)&eWhh, (void*)&eb,
                  (void*)&h0, (void*)&c0, (void*)&dWih, (void*)&dWhh,
                  (void*)&db, (void*)&outW, (void*)&outb, (void*)&out,
                  (void*)&hA, (void*)&hB, (void*)&xT, (void*)&gpart,
                  (void*)&cnt};
  hipLaunchCooperativeKernel((const void*)lstm6, dim3(256), dim3(1024),
                             args, 0, stream);
}